// Round 15
// baseline (219.608 us; speedup 1.0000x reference)
//
#include <hip/hip_runtime.h>

typedef unsigned short u16;
typedef __bf16 bf16x8 __attribute__((ext_vector_type(8)));
typedef float f32x4 __attribute__((ext_vector_type(4)));

// ---------- helpers ----------
__device__ __forceinline__ u16 f2bf(float f) {
  union { float f; unsigned u; } v; v.f = f;
  return (u16)((v.u + 0x7fffu + ((v.u >> 16) & 1u)) >> 16);   // RNE
}

#define GLDS16(g, l)                                                          \
  __builtin_amdgcn_global_load_lds(                                           \
      (const __attribute__((address_space(1))) void*)(g),                     \
      (__attribute__((address_space(3))) void*)(l), 16, 0, 0)

#define SBAR()  __builtin_amdgcn_s_barrier()
#define SCHED() __builtin_amdgcn_sched_barrier(0)
#define VMCNT(n) asm volatile("s_waitcnt vmcnt(" #n ")" ::: "memory")

// ---------- sizes ----------
#define NTOK 4096     // B*T
#define DIM  768
#define HID  1536
#define NEXP 8
#define SLAB 1536     // fixed per-expert slot slab (counts ~1024 +/- 30)
#define CAPR (NEXP * SLAB)   // 12288
#define SHB  CAPR            // shared-expert slot base
#define NSLOT (CAPR + NTOK)  // 16384
#define MAXT2 128     // 128-row M-tiles worst case (both GEMMs)
#define CSTRIDE 32    // cnt padding: one counter per 128B cacheline

// B_cat layout (per expert, [3072 rows][768 K]): row ncat = (c>>4)*32 + mat*16 + (c&15)
// where c = hidden col (0..1535), mat = 0 (w1) / 1 (w2).  Fragment pairs (n,n+1)
// in a 128-row N-tile then hold (w1,w2) of the SAME 16 hidden cols per thread.

// ---------- fused prep: z<18 = B_cat transpose, z<27 = proj transpose, z==27 = router ----
__global__ __launch_bounds__(256) void k_prep(const float* __restrict__ x,
                                              const float* __restrict__ rw,
                                              const float* __restrict__ ew1,
                                              const float* __restrict__ sw1,
                                              const float* __restrict__ ew2,
                                              const float* __restrict__ sw2,
                                              const float* __restrict__ eproj,
                                              const float* __restrict__ sproj,
                                              u16* __restrict__ bcat,
                                              u16* __restrict__ pjt,
                                              u16* __restrict__ xb,
                                              float* __restrict__ probs,
                                              int* __restrict__ cnt,
                                              int* __restrict__ slotTok,
                                              float* __restrict__ slotW,
                                              int* __restrict__ tokSlot) {
  constexpr size_t SL = (size_t)HID * DIM;
  const int z = blockIdx.z;
  if (z < 27) {
    __shared__ u16 tile[64][65];
    const int tx = threadIdx.x, ty = threadIdx.y;   // (64,4)
    if (z < 18) {
      const int mat = (z >= 9) ? 1 : 0;
      const int q = (z >= 9) ? z - 9 : z;
      const float* src = (q < 8) ? ((mat == 0) ? ew1 + (size_t)q * SL : ew2 + (size_t)q * SL)
                                 : ((mat == 0) ? sw1 : sw2);
      u16* dst = bcat + (size_t)q * (2 * SL);
      const int c0 = blockIdx.x * 64, r0 = blockIdx.y * 64;   // c over HID, r over DIM
      #pragma unroll
      for (int i = 0; i < 16; i++)
        tile[ty + 4 * i][tx] = f2bf(src[(size_t)(r0 + ty + 4 * i) * HID + c0 + tx]);
      __syncthreads();
      #pragma unroll
      for (int i = 0; i < 16; i++) {
        const int c = c0 + ty + 4 * i;
        const int ncat = ((c >> 4) << 5) + mat * 16 + (c & 15);
        dst[(size_t)ncat * DIM + r0 + tx] = tile[tx][ty + 4 * i];
      }
    } else {
      const int q = z - 18;
      const float* src = (q < 8) ? eproj + (size_t)q * SL : sproj;
      u16* dst = pjt + (size_t)q * SL;
      const int c0 = blockIdx.y * 64, r0 = blockIdx.x * 64;   // c over DIM, r over HID
      #pragma unroll
      for (int i = 0; i < 16; i++)
        tile[ty + 4 * i][tx] = f2bf(src[(size_t)(r0 + ty + 4 * i) * DIM + c0 + tx]);
      __syncthreads();
      #pragma unroll
      for (int i = 0; i < 16; i++)
        dst[(size_t)(c0 + ty + 4 * i) * HID + r0 + tx] = tile[tx][ty + 4 * i];
    }
    return;
  }
  // ----- router plane: 288 blocks x 4 waves; per-block LDS aggregation (FROZEN r11) ----
  __shared__ int   sI1[16], sI2[16];
  __shared__ float sW1[16], sW2[16];
  const int tid = threadIdx.y * 64 + threadIdx.x;
  const int wv = tid >> 6, lane = tid & 63;
  const int rb = blockIdx.y * 24 + blockIdx.x;     // 0..287
  for (int j = wv; j < 15; j += 4) {
    const int t = rb + 288 * j;
    if (t >= NTOK) continue;
    const float* xr = x + (size_t)t * DIM;
    u16* xbr = xb + (size_t)t * DIM;
    float acc[NEXP] = {0, 0, 0, 0, 0, 0, 0, 0};
    #pragma unroll
    for (int i = 0; i < DIM / 64; i++) {
      const int d = lane + 64 * i;
      const float xv = xr[d];
      xbr[d] = f2bf(xv);
      #pragma unroll
      for (int e = 0; e < NEXP; e++) acc[e] += xv * rw[e * DIM + d];
    }
    #pragma unroll
    for (int e = 0; e < NEXP; e++)
      #pragma unroll
      for (int s = 32; s > 0; s >>= 1) acc[e] += __shfl_xor(acc[e], s, 64);
    if (lane == 0) {
      float mx = acc[0];
      #pragma unroll
      for (int e = 1; e < NEXP; e++) mx = fmaxf(mx, acc[e]);
      float p[NEXP], sum = 0.f;
      #pragma unroll
      for (int e = 0; e < NEXP; e++) { p[e] = expf(acc[e] - mx); sum += p[e]; }
      const float inv = 1.f / sum;
      #pragma unroll
      for (int e = 0; e < NEXP; e++) p[e] *= inv;
      #pragma unroll
      for (int e = 0; e < NEXP; e++) probs[(size_t)t * NEXP + e] = p[e];
      int i1 = 0;
      #pragma unroll
      for (int e = 1; e < NEXP; e++) if (p[e] > p[i1]) i1 = e;
      int i2 = (i1 == 0) ? 1 : 0;
      #pragma unroll
      for (int e = 0; e < NEXP; e++) if (e != i1 && p[e] > p[i2]) i2 = e;
      const float s2 = 1.f / (p[i1] + p[i2]);
      sI1[j] = i1; sI2[j] = i2;
      sW1[j] = p[i1] * s2; sW2[j] = p[i2] * s2;
      slotTok[SHB + t] = t; slotW[SHB + t] = 1.f;
    }
  }
  __syncthreads();
  if (tid < NEXP) {
    const int e = tid;
    int c = 0;
    for (int j = 0; j < 15; j++) {
      const int t = rb + 288 * j;
      if (t < NTOK && (sI1[j] == e || sI2[j] == e)) c++;
    }
    if (c) {
      const int base = atomicAdd(&cnt[e * CSTRIDE], c);
      if (base + c <= SLAB) {
        int k = 0;
        for (int j = 0; j < 15; j++) {
          const int t = rb + 288 * j;
          if (t >= NTOK) continue;
          if (sI1[j] == e) {
            const int s = e * SLAB + base + k;
            slotTok[s] = t; slotW[s] = sW1[j]; tokSlot[2 * t] = s; k++;
          } else if (sI2[j] == e) {
            const int s = e * SLAB + base + k;
            slotTok[s] = t; slotW[s] = sW2[j]; tokSlot[2 * t + 1] = s; k++;
          }
        }
      }
    }
  }
}

// ---------- tile decode from padded cnt (uniform scalar scan) ----------
__device__ __forceinline__ int decode_tile(const int* __restrict__ cnt, int bx,
                                           int rows_log2, int nShared, int* m0out) {
  int e = -1, m0 = 0, acc = 0;
  #pragma unroll
  for (int ee = 0; ee < NEXP; ee++) {
    const int tl = (cnt[ee * CSTRIDE] + ((1 << rows_log2) - 1)) >> rows_log2;
    if (bx >= acc && bx < acc + tl) { e = ee; m0 = ee * SLAB + ((bx - acc) << rows_log2); }
    acc += tl;
  }
  if (e < 0) {
    const int sx = bx - acc;
    if (sx >= 0 && sx < nShared) { e = NEXP; m0 = SHB + (sx << rows_log2); }
  }
  *m0out = m0;
  return e;
}

// ---------- gemm1: 128x128xBK64 single-B_cat, 4 waves, 64KB LDS (2 blk/CU) ----------
// Body FROZEN r13; map = stride-8 bx interleave: balanced for any contiguous
// active prefix AND per-XCD A-slice (16 fixed bx = 3.1MB) stays L2-resident.
__global__ __launch_bounds__(256, 2) void k_gemm1(const u16* __restrict__ xb,
                                                  const u16* __restrict__ bcat,
                                                  const int* __restrict__ cnt,
                                                  const int* __restrict__ slotTok,
                                                  const float* __restrict__ slotW,
                                                  u16* __restrict__ hidden) {
  __shared__ alignas(16) u16 L[2][16384];
  const int bid = blockIdx.x;                      // 3072 = 8 XCD x 16 bxi x 24 by
  const int bx = (bid & 7) + (((bid >> 3) & 15) << 3);   // stride-8 interleave
  const int by = bid >> 7;                               // 0..23
  int m0;
  const int e = decode_tile(cnt, bx, 7, NTOK / 128, &m0);
  if (e < 0) return;
  const int nBase = by * 128;                      // B_cat rows
  constexpr size_t SL = (size_t)HID * DIM;
  const u16* bc = bcat + (size_t)e * (2 * SL);
  const int tid = threadIdx.x, w = tid >> 6, lane = tid & 63;
  const int wr = w >> 1, wc = w & 1;

  const int r0 = tid >> 2;
  const int kcol = ((tid & 3) ^ ((tid >> 3) & 3)) * 8;
  const int tokA0 = slotTok[m0 + r0];
  const int tokA1 = slotTok[m0 + 64 + r0];
  const u16* gA0 = xb + (size_t)tokA0 * DIM + kcol;
  const u16* gA1 = xb + (size_t)tokA1 * DIM + kcol;
  const u16* gB0 = bc + (size_t)(nBase + r0) * DIM + kcol;
  const u16* gB1p = bc + (size_t)(nBase + 64 + r0) * DIM + kcol;
  const int d0 = tid * 8, d1 = 2048 + tid * 8;

  const int rl = lane & 15;
  const int kq = lane >> 4;
  const int aBase = (wr * 64 + rl) * 32 + (kq ^ ((rl >> 1) & 3)) * 8;
  const int bBase = (wc * 64 + rl) * 32 + (kq ^ ((rl >> 1) & 3)) * 8;

  f32x4 acc[4][4];
  const f32x4 vz = {0.f, 0.f, 0.f, 0.f};
  #pragma unroll
  for (int m = 0; m < 4; m++)
    #pragma unroll
    for (int n = 0; n < 4; n++) acc[m][n] = vz;

#define G1_STKH(d, koff, kh) do {                                             \
    GLDS16(gA0 + (koff), &L[d][(kh) * 4096 + d0]);                            \
    GLDS16(gA1 + (koff), &L[d][(kh) * 4096 + d1]);                            \
    GLDS16(gB0 + (koff), &L[d][8192 + (kh) * 4096 + d0]);                     \
    GLDS16(gB1p + (koff), &L[d][8192 + (kh) * 4096 + d1]); } while (0)

#define G1_PH(d, kh, dostage, sd, skh, koff, vm) do {                         \
    bf16x8 av[4], bv[4];                                                      \
    _Pragma("unroll")                                                         \
    for (int n = 0; n < 4; n++)                                               \
      bv[n] = *(const bf16x8*)&L[d][8192 + (kh) * 4096 + bBase + n * 512];    \
    _Pragma("unroll")                                                         \
    for (int m = 0; m < 4; m++)                                               \
      av[m] = *(const bf16x8*)&L[d][(kh) * 4096 + aBase + m * 512];           \
    SCHED();                                                                  \
    if (dostage) { G1_STKH(sd, koff, skh); SCHED(); }                         \
    __builtin_amdgcn_s_setprio(1);                                            \
    _Pragma("unroll")                                                         \
    for (int m = 0; m < 4; m++)                                               \
      _Pragma("unroll")                                                       \
      for (int n = 0; n < 4; n++)                                             \
        acc[m][n] = __builtin_amdgcn_mfma_f32_16x16x32_bf16(av[m], bv[n], acc[m][n], 0, 0, 0); \
    __builtin_amdgcn_s_setprio(0);                                            \
    SCHED(); VMCNT(vm); SBAR(); SCHED();                                      \
  } while (0)

  G1_STKH(0, 0, 0);
  G1_STKH(0, 32, 1);
  G1_STKH(1, 64, 0);
  SCHED(); VMCNT(8); SBAR(); SCHED();

  // NT=12: loop tiles 0..9
  for (int i = 0; i < 5; i++) {
    const int kt = i * 128;
    G1_PH(0, 0, true, 1, 1, kt + 96,  8);
    G1_PH(0, 1, true, 0, 0, kt + 128, 8);
    G1_PH(1, 0, true, 0, 1, kt + 160, 8);
    G1_PH(1, 1, true, 1, 0, kt + 192, 8);
  }
  // tail: tiles 10, 11
  G1_PH(0, 0, true, 1, 1, 736, 8);   // stage kh1(11)
  G1_PH(0, 1, false, 0, 0, 0, 4);
  G1_PH(1, 0, false, 0, 0, 0, 0);
  G1_PH(1, 1, false, 0, 0, 0, 0);
#undef G1_PH
#undef G1_STKH

  // epilogue: acc[m][2p] = w1-product, acc[m][2p+1] = w2-product of hidden cols
  const int hc0 = ((nBase + wc * 64) >> 1) + rl;
  #pragma unroll
  for (int m = 0; m < 4; m++)
    #pragma unroll
    for (int r = 0; r < 4; r++) {
      const int slot = m0 + wr * 64 + m * 16 + (lane >> 4) * 4 + r;
      const float cwv = slotW[slot];
      #pragma unroll
      for (int p = 0; p < 2; p++) {
        const float v1 = acc[m][2 * p][r], v2 = acc[m][2 * p + 1][r];
        hidden[(size_t)slot * HID + hc0 + p * 16] =
            f2bf((v1 / (1.f + __expf(-v1))) * v2 * cwv);
      }
    }
}

// ---------- gemm2: merged fat-phase 128x128xBK64, 4 waves, single-B (FROZEN r12) ----
__global__ __launch_bounds__(256, 2) void k_gemm2(const u16* __restrict__ hid,
                                                  const u16* __restrict__ pjt,
                                                  const int* __restrict__ cnt,
                                                  float* __restrict__ g2) {
  __shared__ alignas(16) u16 L[2][16384];
  const int bid = blockIdx.x;                      // 768 = 8*96
  const int wgid = (bid & 7) * 96 + (bid >> 3);
  const int bx = wgid % MAXT2, by = wgid / MAXT2;
  int m0;
  const int e = decode_tile(cnt, bx, 7, NTOK / 128, &m0);
  if (e < 0) return;
  const int nBase = by * 128;
  constexpr size_t SL = (size_t)HID * DIM;
  const u16* pj = pjt + (size_t)e * SL;
  const int tid = threadIdx.x, w = tid >> 6, lane = tid & 63;
  const int wr = w >> 1, wc = w & 1;

  const int r0 = tid >> 2;
  const int kcol = ((tid & 3) ^ ((tid >> 3) & 3)) * 8;
  const u16* gA0 = hid + (size_t)(m0 + r0) * HID + kcol;
  const u16* gA1 = hid + (size_t)(m0 + 64 + r0) * HID + kcol;
  const u16* gB0 = pj + (size_t)(nBase + r0) * HID + kcol;
  const u16* gB1p = pj + (size_t)(nBase + 64 + r0) * HID + kcol;
  const int d0 = tid * 8, d1 = 2048 + tid * 8;

  const int rl = lane & 15;
  const int kq = lane >> 4;
  const int aBase = (wr * 64 + rl) * 32 + (kq ^ ((rl >> 1) & 3)) * 8;
  const int bBase = (wc * 64 + rl) * 32 + (kq ^ ((rl >> 1) & 3)) * 8;

  f32x4 acc[4][4];
  const f32x4 vz = {0.f, 0.f, 0.f, 0.f};
  #pragma unroll
  for (int m = 0; m < 4; m++)
    #pragma unroll
    for (int n = 0; n < 4; n++) acc[m][n] = vz;

#define G2_STKH(d, koff, kh) do {                                             \
    GLDS16(gA0 + (koff), &L[d][(kh) * 4096 + d0]);                            \
    GLDS16(gA1 + (koff), &L[d][(kh) * 4096 + d1]);                            \
    GLDS16(gB0 + (koff), &L[d][8192 + (kh) * 4096 + d0]);                     \
    GLDS16(gB1p + (koff), &L[d][8192 + (kh) * 4096 + d1]); } while (0)

#define G2_PH(d, kh, dostage, sd, skh, koff, vm) do {                         \
    bf16x8 av[4], bv[4];                                                      \
    _Pragma("unroll")                                                         \
    for (int n = 0; n < 4; n++)                                               \
      bv[n] = *(const bf16x8*)&L[d][8192 + (kh) * 4096 + bBase + n * 512];    \
    _Pragma("unroll")                                                         \
    for (int m = 0; m < 4; m++)                                               \
      av[m] = *(const bf16x8*)&L[d][(kh) * 4096 + aBase + m * 512];           \
    SCHED();                                                                  \
    if (dostage) { G2_STKH(sd, koff, skh); SCHED(); }                         \
    __builtin_amdgcn_s_setprio(1);                                            \
    _Pragma("unroll")                                                         \
    for (int m = 0; m < 4; m++)                                               \
      _Pragma("unroll")                                                       \
      for (int n = 0; n < 4; n++)                                             \
        acc[m][n] = __builtin_amdgcn_mfma_f32_16x16x32_bf16(av[m], bv[n], acc[m][n], 0, 0, 0); \
    __builtin_amdgcn_s_setprio(0);                                            \
    SCHED(); VMCNT(vm); SBAR(); SCHED();                                      \
  } while (0)

  G2_STKH(0, 0, 0);
  G2_STKH(0, 32, 1);
  G2_STKH(1, 64, 0);
  SCHED(); VMCNT(8); SBAR(); SCHED();

  // NT=24: loop tiles 0..21
  for (int i = 0; i < 11; i++) {
    const int kt = i * 128;
    G2_PH(0, 0, true, 1, 1, kt + 96,  8);
    G2_PH(0, 1, true, 0, 0, kt + 128, 8);
    G2_PH(1, 0, true, 0, 1, kt + 160, 8);
    G2_PH(1, 1, true, 1, 0, kt + 192, 8);
  }
  // tail: tiles 22, 23
  G2_PH(0, 0, true, 1, 1, 1504, 8);  // stage kh1(23)
  G2_PH(0, 1, false, 0, 0, 0, 4);
  G2_PH(1, 0, false, 0, 0, 0, 0);
  G2_PH(1, 1, false, 0, 0, 0, 0);
#undef G2_PH
#undef G2_STKH

  #pragma unroll
  for (int m = 0; m < 4; m++)
    #pragma unroll
    for (int r = 0; r < 4; r++) {
      const int slot = m0 + wr * 64 + m * 16 + (lane >> 4) * 4 + r;
      #pragma unroll
      for (int n = 0; n < 4; n++) {
        const int dcol = nBase + wc * 64 + n * 16 + (lane & 15);
        g2[(size_t)slot * DIM + dcol] = acc[m][n][r];
      }
    }
}

// ---------- combine: out[t] = g2[sA] + g2[sB] + g2[shared] ----------
__global__ __launch_bounds__(192) void k_combine(const float* __restrict__ g2,
                                                 const int* __restrict__ tokSlot,
                                                 float* __restrict__ out) {
  const int t = blockIdx.x, d4 = threadIdx.x;
  const int sA = tokSlot[2 * t], sB = tokSlot[2 * t + 1];
  const float4 a = ((const float4*)(g2 + (size_t)sA * DIM))[d4];
  const float4 b = ((const float4*)(g2 + (size_t)sB * DIM))[d4];
  const float4 c = ((const float4*)(g2 + (size_t)(SHB + t) * DIM))[d4];
  float4 o;
  o.x = a.x + b.x + c.x; o.y = a.y + b.y + c.y;
  o.z = a.z + b.z + c.z; o.w = a.w + b.w + c.w;
  ((float4*)(out + (size_t)t * DIM))[d4] = o;
}

// ---------- launch ----------
extern "C" void kernel_launch(void* const* d_in, const int* in_sizes, int n_in,
                              void* d_out, int out_size, void* d_ws, size_t ws_size,
                              hipStream_t stream) {
  const float* x     = (const float*)d_in[0];
  const float* rw    = (const float*)d_in[1];
  const float* sw1   = (const float*)d_in[2];
  const float* sw2   = (const float*)d_in[3];
  const float* sproj = (const float*)d_in[4];
  const float* ew1   = (const float*)d_in[5];
  const float* ew2   = (const float*)d_in[6];
  const float* eproj = (const float*)d_in[7];
  float* out   = (float*)d_out;
  float* probs = out + (size_t)NTOK * DIM;

  constexpr size_t SL = (size_t)HID * DIM;
  constexpr size_t off_xb   = 0;
  constexpr size_t off_bcat = 6291456;                           // 9 x 2SL bf16
  constexpr size_t off_pjt  = off_bcat + 4 * 9 * SL;             // 48,758,784
  constexpr size_t off_hid  = off_pjt + 2 * 9 * SL;              // 69,992,448
  constexpr size_t off_g2   = off_hid + (size_t)NSLOT * HID * 2; // 120,324,096
  constexpr size_t off_meta = off_g2 + (size_t)NSLOT * DIM * 4;  // 170,655,744

  char* ws = (char*)d_ws;
  u16*   xb   = (u16*)(ws + off_xb);
  u16*   bcat = (u16*)(ws + off_bcat);
  u16*   pjt  = (u16*)(ws + off_pjt);
  u16*   hid  = (u16*)(ws + off_hid);
  float* g2   = (float*)(ws + off_g2);
  char*  meta = ws + off_meta;
  int*   cnt     = (int*)meta;                        // 8 counters, 128B apart
  int*   slotTok = (int*)(meta + 1024);               // 65,536
  float* slotW   = (float*)(meta + 1024 + 65536);     // 65,536
  int*   tokSlot = (int*)(meta + 1024 + 131072);      // 32,768

  // zero cnt + slotTok + slotW + tokSlot (determinism across graph replays)
  hipMemsetAsync(meta, 0, 1024 + 131072 + 32768, stream);

  k_prep<<<dim3(HID / 64, DIM / 64, 28), dim3(64, 4), 0, stream>>>(
      x, rw, ew1, sw1, ew2, sw2, eproj, sproj, bcat, pjt, xb,
      probs, cnt, slotTok, slotW, tokSlot);

  k_gemm1<<<MAXT2 * (2 * HID / 128), 256, 0, stream>>>(xb, bcat, cnt,
                                                       slotTok, slotW, hid);
  k_gemm2<<<MAXT2 * (DIM / 128), 256, 0, stream>>>(hid, pjt, cnt, g2);
  k_combine<<<NTOK, 192, 0, stream>>>(g2, tokSlot, out);
}

// Round 16
// 194.143 us; speedup vs baseline: 1.1312x; 1.1312x over previous
//
#include <hip/hip_runtime.h>

typedef unsigned short u16;
typedef __bf16 bf16x8 __attribute__((ext_vector_type(8)));
typedef float f32x4 __attribute__((ext_vector_type(4)));

// ---------- helpers ----------
__device__ __forceinline__ u16 f2bf(float f) {
  union { float f; unsigned u; } v; v.f = f;
  return (u16)((v.u + 0x7fffu + ((v.u >> 16) & 1u)) >> 16);   // RNE
}

#define GLDS16(g, l)                                                          \
  __builtin_amdgcn_global_load_lds(                                           \
      (const __attribute__((address_space(1))) void*)(g),                     \
      (__attribute__((address_space(3))) void*)(l), 16, 0, 0)

#define SBAR()  __builtin_amdgcn_s_barrier()
#define SCHED() __builtin_amdgcn_sched_barrier(0)
#define VMCNT(n) asm volatile("s_waitcnt vmcnt(" #n ")" ::: "memory")

// ---------- sizes ----------
#define NTOK 4096     // B*T
#define DIM  768
#define HID  1536
#define NEXP 8
#define SLAB 1536     // fixed per-expert slot slab (counts ~1024 +/- 30)
#define CAPR (NEXP * SLAB)   // 12288
#define SHB  CAPR            // shared-expert slot base
#define NSLOT (CAPR + NTOK)  // 16384
#define MAXT1 64      // 256-row M-tiles worst case
#define MAXT2 128     // 128-row M-tiles worst case
#define CSTRIDE 32    // cnt padding: one counter per 128B cacheline

// ---------- fused prep: z<27 = weight transpose slices, z==27 = router (FROZEN r11) ----
__global__ __launch_bounds__(256) void k_prep(const float* __restrict__ x,
                                              const float* __restrict__ rw,
                                              const float* __restrict__ ew1,
                                              const float* __restrict__ sw1,
                                              const float* __restrict__ ew2,
                                              const float* __restrict__ sw2,
                                              const float* __restrict__ eproj,
                                              const float* __restrict__ sproj,
                                              u16* __restrict__ dstBase,
                                              u16* __restrict__ xb,
                                              float* __restrict__ probs,
                                              int* __restrict__ cnt,
                                              int* __restrict__ slotTok,
                                              float* __restrict__ slotW,
                                              int* __restrict__ tokSlot) {
  constexpr size_t SL = (size_t)HID * DIM;
  const int z = blockIdx.z;
  if (z < 27) {
    __shared__ u16 tile[64][65];
    const float* src;
    int R, C, bxx = blockIdx.x, byy = blockIdx.y;
    if (z < 9)       { src = (z < 8) ? ew1 + (size_t)z * SL : sw1; R = DIM; C = HID; }
    else if (z < 18) { const int q = z - 9;  src = (q < 8) ? ew2 + (size_t)q * SL : sw2; R = DIM; C = HID; }
    else             { const int q = z - 18; src = (q < 8) ? eproj + (size_t)q * SL : sproj;
                       R = HID; C = DIM; const int t = bxx; bxx = byy; byy = t; }
    u16* dst = dstBase + (size_t)z * SL;
    const int c0 = bxx * 64, r0 = byy * 64;
    const int tx = threadIdx.x, ty = threadIdx.y;   // (64,4)
    #pragma unroll
    for (int i = 0; i < 16; i++)
      tile[ty + 4 * i][tx] = f2bf(src[(size_t)(r0 + ty + 4 * i) * C + c0 + tx]);
    __syncthreads();
    #pragma unroll
    for (int i = 0; i < 16; i++)
      dst[(size_t)(c0 + ty + 4 * i) * R + r0 + tx] = tile[tx][ty + 4 * i];
    return;
  }
  // ----- router plane: 288 blocks x 4 waves; per-block LDS aggregation -----
  __shared__ int   sI1[16], sI2[16];
  __shared__ float sW1[16], sW2[16];
  const int tid = threadIdx.y * 64 + threadIdx.x;
  const int wv = tid >> 6, lane = tid & 63;
  const int rb = blockIdx.y * 24 + blockIdx.x;     // 0..287
  for (int j = wv; j < 15; j += 4) {
    const int t = rb + 288 * j;
    if (t >= NTOK) continue;
    const float* xr = x + (size_t)t * DIM;
    u16* xbr = xb + (size_t)t * DIM;
    float acc[NEXP] = {0, 0, 0, 0, 0, 0, 0, 0};
    #pragma unroll
    for (int i = 0; i < DIM / 64; i++) {
      const int d = lane + 64 * i;
      const float xv = xr[d];
      xbr[d] = f2bf(xv);
      #pragma unroll
      for (int e = 0; e < NEXP; e++) acc[e] += xv * rw[e * DIM + d];
    }
    #pragma unroll
    for (int e = 0; e < NEXP; e++)
      #pragma unroll
      for (int s = 32; s > 0; s >>= 1) acc[e] += __shfl_xor(acc[e], s, 64);
    if (lane == 0) {
      float mx = acc[0];
      #pragma unroll
      for (int e = 1; e < NEXP; e++) mx = fmaxf(mx, acc[e]);
      float p[NEXP], sum = 0.f;
      #pragma unroll
      for (int e = 0; e < NEXP; e++) { p[e] = expf(acc[e] - mx); sum += p[e]; }
      const float inv = 1.f / sum;
      #pragma unroll
      for (int e = 0; e < NEXP; e++) p[e] *= inv;
      #pragma unroll
      for (int e = 0; e < NEXP; e++) probs[(size_t)t * NEXP + e] = p[e];
      int i1 = 0;
      #pragma unroll
      for (int e = 1; e < NEXP; e++) if (p[e] > p[i1]) i1 = e;
      int i2 = (i1 == 0) ? 1 : 0;
      #pragma unroll
      for (int e = 0; e < NEXP; e++) if (e != i1 && p[e] > p[i2]) i2 = e;
      const float s2 = 1.f / (p[i1] + p[i2]);
      sI1[j] = i1; sI2[j] = i2;
      sW1[j] = p[i1] * s2; sW2[j] = p[i2] * s2;
      slotTok[SHB + t] = t; slotW[SHB + t] = 1.f;
    }
  }
  __syncthreads();
  if (tid < NEXP) {
    const int e = tid;
    int c = 0;
    for (int j = 0; j < 15; j++) {
      const int t = rb + 288 * j;
      if (t < NTOK && (sI1[j] == e || sI2[j] == e)) c++;
    }
    if (c) {
      const int base = atomicAdd(&cnt[e * CSTRIDE], c);
      if (base + c <= SLAB) {
        int k = 0;
        for (int j = 0; j < 15; j++) {
          const int t = rb + 288 * j;
          if (t >= NTOK) continue;
          if (sI1[j] == e) {
            const int s = e * SLAB + base + k;
            slotTok[s] = t; slotW[s] = sW1[j]; tokSlot[2 * t] = s; k++;
          } else if (sI2[j] == e) {
            const int s = e * SLAB + base + k;
            slotTok[s] = t; slotW[s] = sW2[j]; tokSlot[2 * t + 1] = s; k++;
          }
        }
      }
    }
  }
}

// ---------- tile decode from padded cnt (uniform scalar scan) ----------
__device__ __forceinline__ int decode_tile(const int* __restrict__ cnt, int bx,
                                           int rows_log2, int nShared, int* m0out) {
  int e = -1, m0 = 0, acc = 0;
  #pragma unroll
  for (int ee = 0; ee < NEXP; ee++) {
    const int tl = (cnt[ee * CSTRIDE] + ((1 << rows_log2) - 1)) >> rows_log2;
    if (bx >= acc && bx < acc + tl) { e = ee; m0 = ee * SLAB + ((bx - acc) << rows_log2); }
    acc += tl;
  }
  if (e < 0) {
    const int sx = bx - acc;
    if (sx >= 0 && sx < nShared) { e = NEXP; m0 = SHB + (sx << rows_log2); }
  }
  *m0out = m0;
  return e;
}

// ---------- gemm1: 8-phase 256x128xBK64, 8 waves (4Mx2N), dual-B (body FROZEN r8) ----
__global__ __launch_bounds__(512, 2) void k_gemm1(const u16* __restrict__ xb,
                                                  const u16* __restrict__ w1t,
                                                  const u16* __restrict__ w2t,
                                                  const int* __restrict__ cnt,
                                                  const int* __restrict__ slotTok,
                                                  const float* __restrict__ slotW,
                                                  u16* __restrict__ hidden) {
  __shared__ alignas(16) u16 L[2][32768];
  const int bid = blockIdx.x;                       // 768 = 8*96
  const int wgid = (bid & 7) * 96 + (bid >> 3);
  const int bx = wgid % MAXT1, by = wgid / MAXT1;
  int m0;
  const int e = decode_tile(cnt, bx, 8, NTOK / 256, &m0);
  if (e < 0) return;
  const int nBase = by * 128;
  constexpr size_t SL = (size_t)HID * DIM;
  const u16* w1 = w1t + (size_t)e * SL;
  const u16* w2 = w2t + (size_t)e * SL;
  const int tid = threadIdx.x, w = tid >> 6, lane = tid & 63;
  const int wr = w >> 1, wc = w & 1;

  const int srow = tid >> 2;
  const int kcol = ((tid & 3) ^ ((tid >> 3) & 3)) * 8;
  const int tokA0 = slotTok[m0 + srow];
  const int tokA1 = slotTok[m0 + 128 + srow];
  const u16* gA0 = xb + (size_t)tokA0 * DIM + kcol;
  const u16* gA1 = xb + (size_t)tokA1 * DIM + kcol;
  const u16* gB1 = w1 + (size_t)(nBase + srow) * DIM + kcol;
  const u16* gB2 = w2 + (size_t)(nBase + srow) * DIM + kcol;
  const int dA0 = tid * 8, dA1 = 4096 + tid * 8, dB = tid * 8;

  const int rl = lane & 15;
  const int kq = lane >> 4;
  const int aBase = (wr * 64 + rl) * 32 + (kq ^ ((rl >> 1) & 3)) * 8;
  const int bBase = (wc * 64 + rl) * 32 + (kq ^ ((rl >> 1) & 3)) * 8;

  f32x4 acc1[4][4], acc2[4][4];
  const f32x4 vz = {0.f, 0.f, 0.f, 0.f};
  #pragma unroll
  for (int m = 0; m < 4; m++)
    #pragma unroll
    for (int n = 0; n < 4; n++) { acc1[m][n] = vz; acc2[m][n] = vz; }

#define G1_STA(d, koff, kh) do {                                              \
    GLDS16(gA0 + (koff), &L[d][(kh) * 8192 + dA0]);                           \
    GLDS16(gA1 + (koff), &L[d][(kh) * 8192 + dA1]); } while (0)
#define G1_STB(d, koff, kh) do {                                              \
    GLDS16(gB1 + (koff), &L[d][16384 + (kh) * 4096 + dB]);                    \
    GLDS16(gB2 + (koff), &L[d][24576 + (kh) * 4096 + dB]); } while (0)
#define G1_RDB(d, kh) do { _Pragma("unroll")                                  \
    for (int n = 0; n < 4; n++) {                                             \
      b1v[n] = *(const bf16x8*)&L[d][16384 + (kh) * 4096 + bBase + n * 512];  \
      b2v[n] = *(const bf16x8*)&L[d][24576 + (kh) * 4096 + bBase + n * 512]; } } while (0)
#define G1_RDA(d, kh, mp) do { _Pragma("unroll")                              \
    for (int j = 0; j < 2; j++)                                               \
      av[j] = *(const bf16x8*)&L[d][(kh) * 8192 + aBase + ((mp) * 2 + j) * 512]; } while (0)
#define G1_MM(mp) do { __builtin_amdgcn_s_setprio(1);                         \
    _Pragma("unroll") for (int j = 0; j < 2; j++)                             \
      _Pragma("unroll") for (int n = 0; n < 4; n++) {                         \
        acc1[(mp) * 2 + j][n] = __builtin_amdgcn_mfma_f32_16x16x32_bf16(av[j], b1v[n], acc1[(mp) * 2 + j][n], 0, 0, 0); \
        acc2[(mp) * 2 + j][n] = __builtin_amdgcn_mfma_f32_16x16x32_bf16(av[j], b2v[n], acc2[(mp) * 2 + j][n], 0, 0, 0); } \
    __builtin_amdgcn_s_setprio(0); } while (0)

  G1_STA(0, 0, 0);  G1_STB(0, 0, 0);
  G1_STA(0, 32, 1); G1_STB(0, 32, 1);
  G1_STA(1, 64, 0); G1_STB(1, 64, 0);
  SCHED(); VMCNT(8); SBAR(); SCHED();

  bf16x8 av[2], b1v[4], b2v[4];
  for (int i = 0; i < 5; i++) {
    const int kOff = i * 128;
    G1_RDB(0, 0); G1_RDA(0, 0, 0); SCHED(); G1_STA(1, kOff + 96, 1); SCHED();
    G1_MM(0); SCHED(); SBAR(); SCHED();
    G1_RDA(0, 0, 1); SCHED(); G1_STB(1, kOff + 96, 1); SCHED();
    G1_MM(1); SCHED(); VMCNT(8); SBAR(); SCHED();
    G1_RDB(0, 1); G1_RDA(0, 1, 0); SCHED(); G1_STA(0, kOff + 128, 0); SCHED();
    G1_MM(0); SCHED(); SBAR(); SCHED();
    G1_RDA(0, 1, 1); SCHED(); G1_STB(0, kOff + 128, 0); SCHED();
    G1_MM(1); SCHED(); VMCNT(8); SBAR(); SCHED();
    G1_RDB(1, 0); G1_RDA(1, 0, 0); SCHED(); G1_STA(0, kOff + 160, 1); SCHED();
    G1_MM(0); SCHED(); SBAR(); SCHED();
    G1_RDA(1, 0, 1); SCHED(); G1_STB(0, kOff + 160, 1); SCHED();
    G1_MM(1); SCHED(); VMCNT(8); SBAR(); SCHED();
    G1_RDB(1, 1); G1_RDA(1, 1, 0); SCHED(); G1_STA(1, kOff + 192, 0); SCHED();
    G1_MM(0); SCHED(); SBAR(); SCHED();
    G1_RDA(1, 1, 1); SCHED(); G1_STB(1, kOff + 192, 0); SCHED();
    G1_MM(1); SCHED(); VMCNT(8); SBAR(); SCHED();
  }
  G1_RDB(0, 0); G1_RDA(0, 0, 0); SCHED(); G1_STA(1, 736, 1); SCHED();
  G1_MM(0); SCHED(); SBAR(); SCHED();
  G1_RDA(0, 0, 1); SCHED(); G1_STB(1, 736, 1); SCHED();
  G1_MM(1); SCHED(); VMCNT(8); SBAR(); SCHED();
  G1_RDB(0, 1); G1_RDA(0, 1, 0); SCHED(); G1_MM(0); SCHED(); SBAR(); SCHED();
  G1_RDA(0, 1, 1); SCHED(); G1_MM(1); SCHED(); VMCNT(4); SBAR(); SCHED();
  G1_RDB(1, 0); G1_RDA(1, 0, 0); SCHED(); G1_MM(0); SCHED(); SBAR(); SCHED();
  G1_RDA(1, 0, 1); SCHED(); G1_MM(1); SCHED(); VMCNT(0); SBAR(); SCHED();
  G1_RDB(1, 1); G1_RDA(1, 1, 0); SCHED(); G1_MM(0); SCHED(); SBAR(); SCHED();
  G1_RDA(1, 1, 1); SCHED(); G1_MM(1);
#undef G1_STA
#undef G1_STB
#undef G1_RDB
#undef G1_RDA
#undef G1_MM

  #pragma unroll
  for (int m = 0; m < 4; m++)
    #pragma unroll
    for (int r = 0; r < 4; r++) {
      const int slot = m0 + wr * 64 + m * 16 + (lane >> 4) * 4 + r;
      const float cwv = slotW[slot];
      #pragma unroll
      for (int n = 0; n < 4; n++) {
        const int hcol = nBase + wc * 64 + n * 16 + (lane & 15);
        const float v1 = acc1[m][n][r], v2 = acc2[m][n][r];
        hidden[(size_t)slot * HID + hcol] = f2bf((v1 / (1.f + __expf(-v1))) * v2 * cwv);
      }
    }
}

// ---------- gemm2: 8-phase 128x128xBK64, 4 waves, single-B (body FROZEN r9) ----------
__global__ __launch_bounds__(256, 2) void k_gemm2(const u16* __restrict__ hid,
                                                  const u16* __restrict__ pjt,
                                                  const int* __restrict__ cnt,
                                                  float* __restrict__ g2) {
  __shared__ alignas(16) u16 L[2][16384];
  const int bid = blockIdx.x;                      // 768 = 8*96
  const int wgid = (bid & 7) * 96 + (bid >> 3);
  const int bx = wgid % MAXT2, by = wgid / MAXT2;
  int m0;
  const int e = decode_tile(cnt, bx, 7, NTOK / 128, &m0);
  if (e < 0) return;
  const int nBase = by * 128;
  constexpr size_t SL = (size_t)HID * DIM;
  const u16* pj = pjt + (size_t)e * SL;
  const int tid = threadIdx.x, w = tid >> 6, lane = tid & 63;
  const int wr = w >> 1, wc = w & 1;

  const int r0 = tid >> 2;
  const int kcol = ((tid & 3) ^ ((tid >> 3) & 3)) * 8;
  const u16* gA0 = hid + (size_t)(m0 + r0) * HID + kcol;
  const u16* gA1 = hid + (size_t)(m0 + 64 + r0) * HID + kcol;
  const u16* gB0 = pj + (size_t)(nBase + r0) * HID + kcol;
  const u16* gB1p = pj + (size_t)(nBase + 64 + r0) * HID + kcol;
  const int d0 = tid * 8, d1 = 2048 + tid * 8;

  const int rl = lane & 15;
  const int kq = lane >> 4;
  const int aBase = (wr * 64 + rl) * 32 + (kq ^ ((rl >> 1) & 3)) * 8;
  const int bBase = (wc * 64 + rl) * 32 + (kq ^ ((rl >> 1) & 3)) * 8;

  f32x4 acc[4][4];
  const f32x4 vz = {0.f, 0.f, 0.f, 0.f};
  #pragma unroll
  for (int m = 0; m < 4; m++)
    #pragma unroll
    for (int n = 0; n < 4; n++) acc[m][n] = vz;

#define G2_STA(d, koff, kh) do {                                              \
    GLDS16(gA0 + (koff), &L[d][(kh) * 4096 + d0]);                            \
    GLDS16(gA1 + (koff), &L[d][(kh) * 4096 + d1]); } while (0)
#define G2_STB(d, koff, kh) do {                                              \
    GLDS16(gB0 + (koff), &L[d][8192 + (kh) * 4096 + d0]);                     \
    GLDS16(gB1p + (koff), &L[d][8192 + (kh) * 4096 + d1]); } while (0)
#define G2_RDB(d, kh) do { _Pragma("unroll")                                  \
    for (int n = 0; n < 4; n++)                                               \
      bv[n] = *(const bf16x8*)&L[d][8192 + (kh) * 4096 + bBase + n * 512]; } while (0)
#define G2_RDA(d, kh, mp) do { _Pragma("unroll")                              \
    for (int j = 0; j < 2; j++)                                               \
      av[j] = *(const bf16x8*)&L[d][(kh) * 4096 + aBase + ((mp) * 2 + j) * 512]; } while (0)
#define G2_MM(mp) do { __builtin_amdgcn_s_setprio(1);                         \
    _Pragma("unroll") for (int j = 0; j < 2; j++)                             \
      _Pragma("unroll") for (int n = 0; n < 4; n++)                           \
        acc[(mp) * 2 + j][n] = __builtin_amdgcn_mfma_f32_16x16x32_bf16(av[j], bv[n], acc[(mp) * 2 + j][n], 0, 0, 0); \
    __builtin_amdgcn_s_setprio(0); } while (0)

  G2_STA(0, 0, 0);  G2_STB(0, 0, 0);
  G2_STA(0, 32, 1); G2_STB(0, 32, 1);
  G2_STA(1, 64, 0); G2_STB(1, 64, 0);
  SCHED(); VMCNT(8); SBAR(); SCHED();

  bf16x8 av[2], bv[4];
  for (int i = 0; i < 11; i++) {
    const int kOff = i * 128;
    G2_RDB(0, 0); G2_RDA(0, 0, 0); SCHED(); G2_STA(1, kOff + 96, 1); SCHED();
    G2_MM(0); SCHED(); SBAR(); SCHED();
    G2_RDA(0, 0, 1); SCHED(); G2_STB(1, kOff + 96, 1); SCHED();
    G2_MM(1); SCHED(); VMCNT(8); SBAR(); SCHED();
    G2_RDB(0, 1); G2_RDA(0, 1, 0); SCHED(); G2_STA(0, kOff + 128, 0); SCHED();
    G2_MM(0); SCHED(); SBAR(); SCHED();
    G2_RDA(0, 1, 1); SCHED(); G2_STB(0, kOff + 128, 0); SCHED();
    G2_MM(1); SCHED(); VMCNT(8); SBAR(); SCHED();
    G2_RDB(1, 0); G2_RDA(1, 0, 0); SCHED(); G2_STA(0, kOff + 160, 1); SCHED();
    G2_MM(0); SCHED(); SBAR(); SCHED();
    G2_RDA(1, 0, 1); SCHED(); G2_STB(0, kOff + 160, 1); SCHED();
    G2_MM(1); SCHED(); VMCNT(8); SBAR(); SCHED();
    G2_RDB(1, 1); G2_RDA(1, 1, 0); SCHED(); G2_STA(1, kOff + 192, 0); SCHED();
    G2_MM(0); SCHED(); SBAR(); SCHED();
    G2_RDA(1, 1, 1); SCHED(); G2_STB(1, kOff + 192, 0); SCHED();
    G2_MM(1); SCHED(); VMCNT(8); SBAR(); SCHED();
  }
  G2_RDB(0, 0); G2_RDA(0, 0, 0); SCHED(); G2_STA(1, 1504, 1); SCHED();
  G2_MM(0); SCHED(); SBAR(); SCHED();
  G2_RDA(0, 0, 1); SCHED(); G2_STB(1, 1504, 1); SCHED();
  G2_MM(1); SCHED(); VMCNT(8); SBAR(); SCHED();
  G2_RDB(0, 1); G2_RDA(0, 1, 0); SCHED(); G2_MM(0); SCHED(); SBAR(); SCHED();
  G2_RDA(0, 1, 1); SCHED(); G2_MM(1); SCHED(); VMCNT(4); SBAR(); SCHED();
  G2_RDB(1, 0); G2_RDA(1, 0, 0); SCHED(); G2_MM(0); SCHED(); SBAR(); SCHED();
  G2_RDA(1, 0, 1); SCHED(); G2_MM(1); SCHED(); VMCNT(0); SBAR(); SCHED();
  G2_RDB(1, 1); G2_RDA(1, 1, 0); SCHED(); G2_MM(0); SCHED(); SBAR(); SCHED();
  G2_RDA(1, 1, 1); SCHED(); G2_MM(1);
#undef G2_STA
#undef G2_STB
#undef G2_RDB
#undef G2_RDA
#undef G2_MM

  #pragma unroll
  for (int m = 0; m < 4; m++)
    #pragma unroll
    for (int r = 0; r < 4; r++) {
      const int slot = m0 + wr * 64 + m * 16 + (lane >> 4) * 4 + r;
      #pragma unroll
      for (int n = 0; n < 4; n++) {
        const int dcol = nBase + wc * 64 + n * 16 + (lane & 15);
        g2[(size_t)slot * DIM + dcol] = acc[m][n][r];
      }
    }
}

// ---------- combine: out[t] = g2[sA] + g2[sB] + g2[shared] ----------
__global__ __launch_bounds__(192) void k_combine(const float* __restrict__ g2,
                                                 const int* __restrict__ tokSlot,
                                                 float* __restrict__ out) {
  const int t = blockIdx.x, d4 = threadIdx.x;
  const int sA = tokSlot[2 * t], sB = tokSlot[2 * t + 1];
  const float4 a = ((const float4*)(g2 + (size_t)sA * DIM))[d4];
  const float4 b = ((const float4*)(g2 + (size_t)sB * DIM))[d4];
  const float4 c = ((const float4*)(g2 + (size_t)(SHB + t) * DIM))[d4];
  float4 o;
  o.x = a.x + b.x + c.x; o.y = a.y + b.y + c.y;
  o.z = a.z + b.z + c.z; o.w = a.w + b.w + c.w;
  ((float4*)(out + (size_t)t * DIM))[d4] = o;
}

// ---------- launch ----------
extern "C" void kernel_launch(void* const* d_in, const int* in_sizes, int n_in,
                              void* d_out, int out_size, void* d_ws, size_t ws_size,
                              hipStream_t stream) {
  const float* x     = (const float*)d_in[0];
  const float* rw    = (const float*)d_in[1];
  const float* sw1   = (const float*)d_in[2];
  const float* sw2   = (const float*)d_in[3];
  const float* sproj = (const float*)d_in[4];
  const float* ew1   = (const float*)d_in[5];
  const float* ew2   = (const float*)d_in[6];
  const float* eproj = (const float*)d_in[7];
  float* out   = (float*)d_out;
  float* probs = out + (size_t)NTOK * DIM;

  constexpr size_t SL = (size_t)HID * DIM;
  constexpr size_t off_xb   = 0;
  constexpr size_t off_w1t  = 6291456;
  constexpr size_t off_w2t  = off_w1t + 2 * 9 * SL;
  constexpr size_t off_pjt  = off_w2t + 2 * 9 * SL;
  constexpr size_t off_hid  = off_pjt + 2 * 9 * SL;              //  69,992,448
  constexpr size_t off_g2   = off_hid + (size_t)NSLOT * HID * 2; // 120,324,096
  constexpr size_t off_meta = off_g2 + (size_t)NSLOT * DIM * 4;  // 170,655,744

  char* ws = (char*)d_ws;
  u16*   xb   = (u16*)(ws + off_xb);
  u16*   w1t  = (u16*)(ws + off_w1t);
  u16*   w2t  = (u16*)(ws + off_w2t);
  u16*   pjt  = (u16*)(ws + off_pjt);
  u16*   hid  = (u16*)(ws + off_hid);
  float* g2   = (float*)(ws + off_g2);
  char*  meta = ws + off_meta;
  int*   cnt     = (int*)meta;                        // 8 counters, 128B apart
  int*   slotTok = (int*)(meta + 1024);               // 65,536
  float* slotW   = (float*)(meta + 1024 + 65536);     // 65,536
  int*   tokSlot = (int*)(meta + 1024 + 131072);      // 32,768

  // zero cnt + slotTok + slotW + tokSlot (determinism across graph replays)
  hipMemsetAsync(meta, 0, 1024 + 131072 + 32768, stream);

  k_prep<<<dim3(HID / 64, DIM / 64, 28), dim3(64, 4), 0, stream>>>(
      x, rw, ew1, sw1, ew2, sw2, eproj, sproj, w1t, xb,
      probs, cnt, slotTok, slotW, tokSlot);

  k_gemm1<<<MAXT1 * (HID / 128), 512, 0, stream>>>(xb, w1t, w2t, cnt,
                                                   slotTok, slotW, hid);
  k_gemm2<<<MAXT2 * (DIM / 128), 256, 0, stream>>>(hid, pjt, cnt, g2);
  k_combine<<<NTOK, 192, 0, stream>>>(g2, tokSlot, out);
}

// Round 17
// 189.873 us; speedup vs baseline: 1.1566x; 1.0225x over previous
//
#include <hip/hip_runtime.h>

typedef unsigned short u16;
typedef __bf16 bf16x8 __attribute__((ext_vector_type(8)));
typedef float f32x4 __attribute__((ext_vector_type(4)));

// ---------- helpers ----------
__device__ __forceinline__ u16 f2bf(float f) {
  union { float f; unsigned u; } v; v.f = f;
  return (u16)((v.u + 0x7fffu + ((v.u >> 16) & 1u)) >> 16);   // RNE
}
__device__ __forceinline__ float bf2f(u16 h) {
  union { unsigned u; float f; } v; v.u = ((unsigned)h) << 16;
  return v.f;
}

#define GLDS16(g, l)                                                          \
  __builtin_amdgcn_global_load_lds(                                           \
      (const __attribute__((address_space(1))) void*)(g),                     \
      (__attribute__((address_space(3))) void*)(l), 16, 0, 0)

#define SBAR()  __builtin_amdgcn_s_barrier()
#define SCHED() __builtin_amdgcn_sched_barrier(0)
#define VMCNT(n) asm volatile("s_waitcnt vmcnt(" #n ")" ::: "memory")

// ---------- sizes ----------
#define NTOK 4096     // B*T
#define DIM  768
#define HID  1536
#define NEXP 8
#define SLAB 1536     // fixed per-expert slot slab (counts ~1024 +/- 30)
#define CAPR (NEXP * SLAB)   // 12288
#define SHB  CAPR            // shared-expert slot base
#define NSLOT (CAPR + NTOK)  // 16384
#define MAXT1 64      // 256-row M-tiles worst case
#define MAXT2 128     // 128-row M-tiles worst case
#define CSTRIDE 32    // cnt padding: one counter per 128B cacheline

// ---------- fused prep: z<27 = weight transpose slices, z==27 = router (FROZEN r11) ----
__global__ __launch_bounds__(256) void k_prep(const float* __restrict__ x,
                                              const float* __restrict__ rw,
                                              const float* __restrict__ ew1,
                                              const float* __restrict__ sw1,
                                              const float* __restrict__ ew2,
                                              const float* __restrict__ sw2,
                                              const float* __restrict__ eproj,
                                              const float* __restrict__ sproj,
                                              u16* __restrict__ dstBase,
                                              u16* __restrict__ xb,
                                              float* __restrict__ probs,
                                              int* __restrict__ cnt,
                                              int* __restrict__ slotTok,
                                              float* __restrict__ slotW,
                                              int* __restrict__ tokSlot) {
  constexpr size_t SL = (size_t)HID * DIM;
  const int z = blockIdx.z;
  if (z < 27) {
    __shared__ u16 tile[64][65];
    const float* src;
    int R, C, bxx = blockIdx.x, byy = blockIdx.y;
    if (z < 9)       { src = (z < 8) ? ew1 + (size_t)z * SL : sw1; R = DIM; C = HID; }
    else if (z < 18) { const int q = z - 9;  src = (q < 8) ? ew2 + (size_t)q * SL : sw2; R = DIM; C = HID; }
    else             { const int q = z - 18; src = (q < 8) ? eproj + (size_t)q * SL : sproj;
                       R = HID; C = DIM; const int t = bxx; bxx = byy; byy = t; }
    u16* dst = dstBase + (size_t)z * SL;
    const int c0 = bxx * 64, r0 = byy * 64;
    const int tx = threadIdx.x, ty = threadIdx.y;   // (64,4)
    #pragma unroll
    for (int i = 0; i < 16; i++)
      tile[ty + 4 * i][tx] = f2bf(src[(size_t)(r0 + ty + 4 * i) * C + c0 + tx]);
    __syncthreads();
    #pragma unroll
    for (int i = 0; i < 16; i++)
      dst[(size_t)(c0 + ty + 4 * i) * R + r0 + tx] = tile[tx][ty + 4 * i];
    return;
  }
  // ----- router plane: 288 blocks x 4 waves; per-block LDS aggregation -----
  __shared__ int   sI1[16], sI2[16];
  __shared__ float sW1[16], sW2[16];
  const int tid = threadIdx.y * 64 + threadIdx.x;
  const int wv = tid >> 6, lane = tid & 63;
  const int rb = blockIdx.y * 24 + blockIdx.x;     // 0..287
  for (int j = wv; j < 15; j += 4) {
    const int t = rb + 288 * j;
    if (t >= NTOK) continue;
    const float* xr = x + (size_t)t * DIM;
    u16* xbr = xb + (size_t)t * DIM;
    float acc[NEXP] = {0, 0, 0, 0, 0, 0, 0, 0};
    #pragma unroll
    for (int i = 0; i < DIM / 64; i++) {
      const int d = lane + 64 * i;
      const float xv = xr[d];
      xbr[d] = f2bf(xv);
      #pragma unroll
      for (int e = 0; e < NEXP; e++) acc[e] += xv * rw[e * DIM + d];
    }
    #pragma unroll
    for (int e = 0; e < NEXP; e++)
      #pragma unroll
      for (int s = 32; s > 0; s >>= 1) acc[e] += __shfl_xor(acc[e], s, 64);
    if (lane == 0) {
      float mx = acc[0];
      #pragma unroll
      for (int e = 1; e < NEXP; e++) mx = fmaxf(mx, acc[e]);
      float p[NEXP], sum = 0.f;
      #pragma unroll
      for (int e = 0; e < NEXP; e++) { p[e] = expf(acc[e] - mx); sum += p[e]; }
      const float inv = 1.f / sum;
      #pragma unroll
      for (int e = 0; e < NEXP; e++) p[e] *= inv;
      #pragma unroll
      for (int e = 0; e < NEXP; e++) probs[(size_t)t * NEXP + e] = p[e];
      int i1 = 0;
      #pragma unroll
      for (int e = 1; e < NEXP; e++) if (p[e] > p[i1]) i1 = e;
      int i2 = (i1 == 0) ? 1 : 0;
      #pragma unroll
      for (int e = 0; e < NEXP; e++) if (e != i1 && p[e] > p[i2]) i2 = e;
      const float s2 = 1.f / (p[i1] + p[i2]);
      sI1[j] = i1; sI2[j] = i2;
      sW1[j] = p[i1] * s2; sW2[j] = p[i2] * s2;
      slotTok[SHB + t] = t; slotW[SHB + t] = 1.f;
    }
  }
  __syncthreads();
  if (tid < NEXP) {
    const int e = tid;
    int c = 0;
    for (int j = 0; j < 15; j++) {
      const int t = rb + 288 * j;
      if (t < NTOK && (sI1[j] == e || sI2[j] == e)) c++;
    }
    if (c) {
      const int base = atomicAdd(&cnt[e * CSTRIDE], c);
      if (base + c <= SLAB) {
        int k = 0;
        for (int j = 0; j < 15; j++) {
          const int t = rb + 288 * j;
          if (t >= NTOK) continue;
          if (sI1[j] == e) {
            const int s = e * SLAB + base + k;
            slotTok[s] = t; slotW[s] = sW1[j]; tokSlot[2 * t] = s; k++;
          } else if (sI2[j] == e) {
            const int s = e * SLAB + base + k;
            slotTok[s] = t; slotW[s] = sW2[j]; tokSlot[2 * t + 1] = s; k++;
          }
        }
      }
    }
  }
}

// ---------- tile decode from padded cnt (uniform scalar scan) ----------
__device__ __forceinline__ int decode_tile(const int* __restrict__ cnt, int bx,
                                           int rows_log2, int nShared, int* m0out) {
  int e = -1, m0 = 0, acc = 0;
  #pragma unroll
  for (int ee = 0; ee < NEXP; ee++) {
    const int tl = (cnt[ee * CSTRIDE] + ((1 << rows_log2) - 1)) >> rows_log2;
    if (bx >= acc && bx < acc + tl) { e = ee; m0 = ee * SLAB + ((bx - acc) << rows_log2); }
    acc += tl;
  }
  if (e < 0) {
    const int sx = bx - acc;
    if (sx >= 0 && sx < nShared) { e = NEXP; m0 = SHB + (sx << rows_log2); }
  }
  *m0out = m0;
  return e;
}

// ---------- gemm1: 8-phase 256x128xBK64, 8 waves (4Mx2N), dual-B (body FROZEN r8) ----
__global__ __launch_bounds__(512, 2) void k_gemm1(const u16* __restrict__ xb,
                                                  const u16* __restrict__ w1t,
                                                  const u16* __restrict__ w2t,
                                                  const int* __restrict__ cnt,
                                                  const int* __restrict__ slotTok,
                                                  const float* __restrict__ slotW,
                                                  u16* __restrict__ hidden) {
  __shared__ alignas(16) u16 L[2][32768];
  const int bid = blockIdx.x;                       // 768 = 8*96
  const int wgid = (bid & 7) * 96 + (bid >> 3);
  const int bx = wgid % MAXT1, by = wgid / MAXT1;
  int m0;
  const int e = decode_tile(cnt, bx, 8, NTOK / 256, &m0);
  if (e < 0) return;
  const int nBase = by * 128;
  constexpr size_t SL = (size_t)HID * DIM;
  const u16* w1 = w1t + (size_t)e * SL;
  const u16* w2 = w2t + (size_t)e * SL;
  const int tid = threadIdx.x, w = tid >> 6, lane = tid & 63;
  const int wr = w >> 1, wc = w & 1;

  const int srow = tid >> 2;
  const int kcol = ((tid & 3) ^ ((tid >> 3) & 3)) * 8;
  const int tokA0 = slotTok[m0 + srow];
  const int tokA1 = slotTok[m0 + 128 + srow];
  const u16* gA0 = xb + (size_t)tokA0 * DIM + kcol;
  const u16* gA1 = xb + (size_t)tokA1 * DIM + kcol;
  const u16* gB1 = w1 + (size_t)(nBase + srow) * DIM + kcol;
  const u16* gB2 = w2 + (size_t)(nBase + srow) * DIM + kcol;
  const int dA0 = tid * 8, dA1 = 4096 + tid * 8, dB = tid * 8;

  const int rl = lane & 15;
  const int kq = lane >> 4;
  const int aBase = (wr * 64 + rl) * 32 + (kq ^ ((rl >> 1) & 3)) * 8;
  const int bBase = (wc * 64 + rl) * 32 + (kq ^ ((rl >> 1) & 3)) * 8;

  f32x4 acc1[4][4], acc2[4][4];
  const f32x4 vz = {0.f, 0.f, 0.f, 0.f};
  #pragma unroll
  for (int m = 0; m < 4; m++)
    #pragma unroll
    for (int n = 0; n < 4; n++) { acc1[m][n] = vz; acc2[m][n] = vz; }

#define G1_STA(d, koff, kh) do {                                              \
    GLDS16(gA0 + (koff), &L[d][(kh) * 8192 + dA0]);                           \
    GLDS16(gA1 + (koff), &L[d][(kh) * 8192 + dA1]); } while (0)
#define G1_STB(d, koff, kh) do {                                              \
    GLDS16(gB1 + (koff), &L[d][16384 + (kh) * 4096 + dB]);                    \
    GLDS16(gB2 + (koff), &L[d][24576 + (kh) * 4096 + dB]); } while (0)
#define G1_RDB(d, kh) do { _Pragma("unroll")                                  \
    for (int n = 0; n < 4; n++) {                                             \
      b1v[n] = *(const bf16x8*)&L[d][16384 + (kh) * 4096 + bBase + n * 512];  \
      b2v[n] = *(const bf16x8*)&L[d][24576 + (kh) * 4096 + bBase + n * 512]; } } while (0)
#define G1_RDA(d, kh, mp) do { _Pragma("unroll")                              \
    for (int j = 0; j < 2; j++)                                               \
      av[j] = *(const bf16x8*)&L[d][(kh) * 8192 + aBase + ((mp) * 2 + j) * 512]; } while (0)
#define G1_MM(mp) do { __builtin_amdgcn_s_setprio(1);                         \
    _Pragma("unroll") for (int j = 0; j < 2; j++)                             \
      _Pragma("unroll") for (int n = 0; n < 4; n++) {                         \
        acc1[(mp) * 2 + j][n] = __builtin_amdgcn_mfma_f32_16x16x32_bf16(av[j], b1v[n], acc1[(mp) * 2 + j][n], 0, 0, 0); \
        acc2[(mp) * 2 + j][n] = __builtin_amdgcn_mfma_f32_16x16x32_bf16(av[j], b2v[n], acc2[(mp) * 2 + j][n], 0, 0, 0); } \
    __builtin_amdgcn_s_setprio(0); } while (0)

  G1_STA(0, 0, 0);  G1_STB(0, 0, 0);
  G1_STA(0, 32, 1); G1_STB(0, 32, 1);
  G1_STA(1, 64, 0); G1_STB(1, 64, 0);
  SCHED(); VMCNT(8); SBAR(); SCHED();

  bf16x8 av[2], b1v[4], b2v[4];
  for (int i = 0; i < 5; i++) {
    const int kOff = i * 128;
    G1_RDB(0, 0); G1_RDA(0, 0, 0); SCHED(); G1_STA(1, kOff + 96, 1); SCHED();
    G1_MM(0); SCHED(); SBAR(); SCHED();
    G1_RDA(0, 0, 1); SCHED(); G1_STB(1, kOff + 96, 1); SCHED();
    G1_MM(1); SCHED(); VMCNT(8); SBAR(); SCHED();
    G1_RDB(0, 1); G1_RDA(0, 1, 0); SCHED(); G1_STA(0, kOff + 128, 0); SCHED();
    G1_MM(0); SCHED(); SBAR(); SCHED();
    G1_RDA(0, 1, 1); SCHED(); G1_STB(0, kOff + 128, 0); SCHED();
    G1_MM(1); SCHED(); VMCNT(8); SBAR(); SCHED();
    G1_RDB(1, 0); G1_RDA(1, 0, 0); SCHED(); G1_STA(0, kOff + 160, 1); SCHED();
    G1_MM(0); SCHED(); SBAR(); SCHED();
    G1_RDA(1, 0, 1); SCHED(); G1_STB(0, kOff + 160, 1); SCHED();
    G1_MM(1); SCHED(); VMCNT(8); SBAR(); SCHED();
    G1_RDB(1, 1); G1_RDA(1, 1, 0); SCHED(); G1_STA(1, kOff + 192, 0); SCHED();
    G1_MM(0); SCHED(); SBAR(); SCHED();
    G1_RDA(1, 1, 1); SCHED(); G1_STB(1, kOff + 192, 0); SCHED();
    G1_MM(1); SCHED(); VMCNT(8); SBAR(); SCHED();
  }
  G1_RDB(0, 0); G1_RDA(0, 0, 0); SCHED(); G1_STA(1, 736, 1); SCHED();
  G1_MM(0); SCHED(); SBAR(); SCHED();
  G1_RDA(0, 0, 1); SCHED(); G1_STB(1, 736, 1); SCHED();
  G1_MM(1); SCHED(); VMCNT(8); SBAR(); SCHED();
  G1_RDB(0, 1); G1_RDA(0, 1, 0); SCHED(); G1_MM(0); SCHED(); SBAR(); SCHED();
  G1_RDA(0, 1, 1); SCHED(); G1_MM(1); SCHED(); VMCNT(4); SBAR(); SCHED();
  G1_RDB(1, 0); G1_RDA(1, 0, 0); SCHED(); G1_MM(0); SCHED(); SBAR(); SCHED();
  G1_RDA(1, 0, 1); SCHED(); G1_MM(1); SCHED(); VMCNT(0); SBAR(); SCHED();
  G1_RDB(1, 1); G1_RDA(1, 1, 0); SCHED(); G1_MM(0); SCHED(); SBAR(); SCHED();
  G1_RDA(1, 1, 1); SCHED(); G1_MM(1);
#undef G1_STA
#undef G1_STB
#undef G1_RDB
#undef G1_RDA
#undef G1_MM

  #pragma unroll
  for (int m = 0; m < 4; m++)
    #pragma unroll
    for (int r = 0; r < 4; r++) {
      const int slot = m0 + wr * 64 + m * 16 + (lane >> 4) * 4 + r;
      const float cwv = slotW[slot];
      #pragma unroll
      for (int n = 0; n < 4; n++) {
        const int hcol = nBase + wc * 64 + n * 16 + (lane & 15);
        const float v1 = acc1[m][n][r], v2 = acc2[m][n][r];
        hidden[(size_t)slot * HID + hcol] = f2bf((v1 / (1.f + __expf(-v1))) * v2 * cwv);
      }
    }
}

// ---------- gemm2: 8-phase 128x128xBK64, 4 waves, single-B (body FROZEN r9),
//            epilogue now writes bf16 g2 ----------
__global__ __launch_bounds__(256, 2) void k_gemm2(const u16* __restrict__ hid,
                                                  const u16* __restrict__ pjt,
                                                  const int* __restrict__ cnt,
                                                  u16* __restrict__ g2) {
  __shared__ alignas(16) u16 L[2][16384];
  const int bid = blockIdx.x;                      // 768 = 8*96
  const int wgid = (bid & 7) * 96 + (bid >> 3);
  const int bx = wgid % MAXT2, by = wgid / MAXT2;
  int m0;
  const int e = decode_tile(cnt, bx, 7, NTOK / 128, &m0);
  if (e < 0) return;
  const int nBase = by * 128;
  constexpr size_t SL = (size_t)HID * DIM;
  const u16* pj = pjt + (size_t)e * SL;
  const int tid = threadIdx.x, w = tid >> 6, lane = tid & 63;
  const int wr = w >> 1, wc = w & 1;

  const int r0 = tid >> 2;
  const int kcol = ((tid & 3) ^ ((tid >> 3) & 3)) * 8;
  const u16* gA0 = hid + (size_t)(m0 + r0) * HID + kcol;
  const u16* gA1 = hid + (size_t)(m0 + 64 + r0) * HID + kcol;
  const u16* gB0 = pj + (size_t)(nBase + r0) * HID + kcol;
  const u16* gB1p = pj + (size_t)(nBase + 64 + r0) * HID + kcol;
  const int d0 = tid * 8, d1 = 2048 + tid * 8;

  const int rl = lane & 15;
  const int kq = lane >> 4;
  const int aBase = (wr * 64 + rl) * 32 + (kq ^ ((rl >> 1) & 3)) * 8;
  const int bBase = (wc * 64 + rl) * 32 + (kq ^ ((rl >> 1) & 3)) * 8;

  f32x4 acc[4][4];
  const f32x4 vz = {0.f, 0.f, 0.f, 0.f};
  #pragma unroll
  for (int m = 0; m < 4; m++)
    #pragma unroll
    for (int n = 0; n < 4; n++) acc[m][n] = vz;

#define G2_STA(d, koff, kh) do {                                              \
    GLDS16(gA0 + (koff), &L[d][(kh) * 4096 + d0]);                            \
    GLDS16(gA1 + (koff), &L[d][(kh) * 4096 + d1]); } while (0)
#define G2_STB(d, koff, kh) do {                                              \
    GLDS16(gB0 + (koff), &L[d][8192 + (kh) * 4096 + d0]);                     \
    GLDS16(gB1p + (koff), &L[d][8192 + (kh) * 4096 + d1]); } while (0)
#define G2_RDB(d, kh) do { _Pragma("unroll")                                  \
    for (int n = 0; n < 4; n++)                                               \
      bv[n] = *(const bf16x8*)&L[d][8192 + (kh) * 4096 + bBase + n * 512]; } while (0)
#define G2_RDA(d, kh, mp) do { _Pragma("unroll")                              \
    for (int j = 0; j < 2; j++)                                               \
      av[j] = *(const bf16x8*)&L[d][(kh) * 4096 + aBase + ((mp) * 2 + j) * 512]; } while (0)
#define G2_MM(mp) do { __builtin_amdgcn_s_setprio(1);                         \
    _Pragma("unroll") for (int j = 0; j < 2; j++)                             \
      _Pragma("unroll") for (int n = 0; n < 4; n++)                           \
        acc[(mp) * 2 + j][n] = __builtin_amdgcn_mfma_f32_16x16x32_bf16(av[j], bv[n], acc[(mp) * 2 + j][n], 0, 0, 0); \
    __builtin_amdgcn_s_setprio(0); } while (0)

  G2_STA(0, 0, 0);  G2_STB(0, 0, 0);
  G2_STA(0, 32, 1); G2_STB(0, 32, 1);
  G2_STA(1, 64, 0); G2_STB(1, 64, 0);
  SCHED(); VMCNT(8); SBAR(); SCHED();

  bf16x8 av[2], bv[4];
  for (int i = 0; i < 11; i++) {
    const int kOff = i * 128;
    G2_RDB(0, 0); G2_RDA(0, 0, 0); SCHED(); G2_STA(1, kOff + 96, 1); SCHED();
    G2_MM(0); SCHED(); SBAR(); SCHED();
    G2_RDA(0, 0, 1); SCHED(); G2_STB(1, kOff + 96, 1); SCHED();
    G2_MM(1); SCHED(); VMCNT(8); SBAR(); SCHED();
    G2_RDB(0, 1); G2_RDA(0, 1, 0); SCHED(); G2_STA(0, kOff + 128, 0); SCHED();
    G2_MM(0); SCHED(); SBAR(); SCHED();
    G2_RDA(0, 1, 1); SCHED(); G2_STB(0, kOff + 128, 0); SCHED();
    G2_MM(1); SCHED(); VMCNT(8); SBAR(); SCHED();
    G2_RDB(1, 0); G2_RDA(1, 0, 0); SCHED(); G2_STA(0, kOff + 160, 1); SCHED();
    G2_MM(0); SCHED(); SBAR(); SCHED();
    G2_RDA(1, 0, 1); SCHED(); G2_STB(0, kOff + 160, 1); SCHED();
    G2_MM(1); SCHED(); VMCNT(8); SBAR(); SCHED();
    G2_RDB(1, 1); G2_RDA(1, 1, 0); SCHED(); G2_STA(1, kOff + 192, 0); SCHED();
    G2_MM(0); SCHED(); SBAR(); SCHED();
    G2_RDA(1, 1, 1); SCHED(); G2_STB(1, kOff + 192, 0); SCHED();
    G2_MM(1); SCHED(); VMCNT(8); SBAR(); SCHED();
  }
  G2_RDB(0, 0); G2_RDA(0, 0, 0); SCHED(); G2_STA(1, 1504, 1); SCHED();
  G2_MM(0); SCHED(); SBAR(); SCHED();
  G2_RDA(0, 0, 1); SCHED(); G2_STB(1, 1504, 1); SCHED();
  G2_MM(1); SCHED(); VMCNT(8); SBAR(); SCHED();
  G2_RDB(0, 1); G2_RDA(0, 1, 0); SCHED(); G2_MM(0); SCHED(); SBAR(); SCHED();
  G2_RDA(0, 1, 1); SCHED(); G2_MM(1); SCHED(); VMCNT(4); SBAR(); SCHED();
  G2_RDB(1, 0); G2_RDA(1, 0, 0); SCHED(); G2_MM(0); SCHED(); SBAR(); SCHED();
  G2_RDA(1, 0, 1); SCHED(); G2_MM(1); SCHED(); VMCNT(0); SBAR(); SCHED();
  G2_RDB(1, 1); G2_RDA(1, 1, 0); SCHED(); G2_MM(0); SCHED(); SBAR(); SCHED();
  G2_RDA(1, 1, 1); SCHED(); G2_MM(1);
#undef G2_STA
#undef G2_STB
#undef G2_RDB
#undef G2_RDA
#undef G2_MM

  #pragma unroll
  for (int m = 0; m < 4; m++)
    #pragma unroll
    for (int r = 0; r < 4; r++) {
      const int slot = m0 + wr * 64 + m * 16 + (lane >> 4) * 4 + r;
      #pragma unroll
      for (int n = 0; n < 4; n++) {
        const int dcol = nBase + wc * 64 + n * 16 + (lane & 15);
        g2[(size_t)slot * DIM + dcol] = f2bf(acc[m][n][r]);
      }
    }
}

// ---------- combine: out[t] = g2[sA] + g2[sB] + g2[shared]  (bf16 inputs) ----------
__global__ __launch_bounds__(192) void k_combine(const u16* __restrict__ g2,
                                                 const int* __restrict__ tokSlot,
                                                 float* __restrict__ out) {
  const int t = blockIdx.x, d4 = threadIdx.x;
  const int sA = tokSlot[2 * t], sB = tokSlot[2 * t + 1];
  const ushort4 a = ((const ushort4*)(g2 + (size_t)sA * DIM))[d4];
  const ushort4 b = ((const ushort4*)(g2 + (size_t)sB * DIM))[d4];
  const ushort4 c = ((const ushort4*)(g2 + (size_t)(SHB + t) * DIM))[d4];
  float4 o;
  o.x = bf2f(a.x) + bf2f(b.x) + bf2f(c.x);
  o.y = bf2f(a.y) + bf2f(b.y) + bf2f(c.y);
  o.z = bf2f(a.z) + bf2f(b.z) + bf2f(c.z);
  o.w = bf2f(a.w) + bf2f(b.w) + bf2f(c.w);
  ((float4*)(out + (size_t)t * DIM))[d4] = o;
}

// ---------- launch ----------
extern "C" void kernel_launch(void* const* d_in, const int* in_sizes, int n_in,
                              void* d_out, int out_size, void* d_ws, size_t ws_size,
                              hipStream_t stream) {
  const float* x     = (const float*)d_in[0];
  const float* rw    = (const float*)d_in[1];
  const float* sw1   = (const float*)d_in[2];
  const float* sw2   = (const float*)d_in[3];
  const float* sproj = (const float*)d_in[4];
  const float* ew1   = (const float*)d_in[5];
  const float* ew2   = (const float*)d_in[6];
  const float* eproj = (const float*)d_in[7];
  float* out   = (float*)d_out;
  float* probs = out + (size_t)NTOK * DIM;

  constexpr size_t SL = (size_t)HID * DIM;
  constexpr size_t off_xb   = 0;
  constexpr size_t off_w1t  = 6291456;
  constexpr size_t off_w2t  = off_w1t + 2 * 9 * SL;
  constexpr size_t off_pjt  = off_w2t + 2 * 9 * SL;
  constexpr size_t off_hid  = off_pjt + 2 * 9 * SL;              //  69,992,448
  constexpr size_t off_g2   = off_hid + (size_t)NSLOT * HID * 2; // 120,324,096
  constexpr size_t off_meta = off_g2 + (size_t)NSLOT * DIM * 2;  // (bf16 g2)

  char* ws = (char*)d_ws;
  u16*   xb   = (u16*)(ws + off_xb);
  u16*   w1t  = (u16*)(ws + off_w1t);
  u16*   w2t  = (u16*)(ws + off_w2t);
  u16*   pjt  = (u16*)(ws + off_pjt);
  u16*   hid  = (u16*)(ws + off_hid);
  u16*   g2   = (u16*)(ws + off_g2);
  char*  meta = ws + off_meta;
  int*   cnt     = (int*)meta;                        // 8 counters, 128B apart
  int*   slotTok = (int*)(meta + 1024);               // 65,536
  float* slotW   = (float*)(meta + 1024 + 65536);     // 65,536
  int*   tokSlot = (int*)(meta + 1024 + 131072);      // 32,768

  // zero cnt + slotTok + slotW + tokSlot (determinism across graph replays)
  hipMemsetAsync(meta, 0, 1024 + 131072 + 32768, stream);

  k_prep<<<dim3(HID / 64, DIM / 64, 28), dim3(64, 4), 0, stream>>>(
      x, rw, ew1, sw1, ew2, sw2, eproj, sproj, w1t, xb,
      probs, cnt, slotTok, slotW, tokSlot);

  k_gemm1<<<MAXT1 * (HID / 128), 512, 0, stream>>>(xb, w1t, w2t, cnt,
                                                   slotTok, slotW, hid);
  k_gemm2<<<MAXT2 * (DIM / 128), 256, 0, stream>>>(hid, pjt, cnt, g2);
  k_combine<<<NTOK, 192, 0, stream>>>(g2, tokSlot, out);
}